// Round 3
// baseline (83.841 us; speedup 1.0000x reference)
//
#include <hip/hip_runtime.h>
#include <stdint.h>

// Problem constants
constexpr int Dn = 10000;
constexpr int Bn = 128;
constexpr int Wn = 512;
constexpr int Hn = 128;
constexpr int CAP = 65536;       // ambiguous-list capacity

typedef float f32x2 __attribute__((ext_vector_type(2)));

// ---------------------------------------------------------------------------
// Kernel 1: h-reduction, 4-way h-split for occupancy.
// part[hq][w*128+b] = sum_{h in hq*32..+32} x[b][h][w]  (fp64)
// 512 blocks x 256 threads; float2 loads. Also zeroes the ambiguous counter.
// ---------------------------------------------------------------------------
__global__ __launch_bounds__(256) void reduce_h(const float* __restrict__ x,
                                                double* __restrict__ part,
                                                uint32_t* __restrict__ cnt) {
    if (blockIdx.x == 0 && threadIdx.x == 0) *cnt = 0;
    int tid = blockIdx.x * 256 + threadIdx.x;   // 0 .. 131071
    int hq  = tid >> 15;                        // 0..3
    int rem = tid & 32767;
    int b   = rem >> 8;                         // 0..127
    int wp  = rem & 255;                        // w = 2*wp
    const float2* p = (const float2*)(x + (size_t)b * Hn * Wn + (size_t)(hq * 32) * Wn) + wp;
    double a0 = 0.0, a1 = 0.0;
    #pragma unroll 8
    for (int h = 0; h < 32; ++h) {
        float2 f = p[(size_t)h * (Wn / 2)];
        a0 += (double)f.x;
        a1 += (double)f.y;
    }
    double* pp = part + (size_t)hq * (Wn * Bn);
    pp[(2 * wp)     * Bn + b] = a0;
    pp[(2 * wp + 1) * Bn + b] = a1;
}

// ---------------------------------------------------------------------------
// Kernel 2 (fused): blocks 0..255 combine the 4 h-partials -> sT64 + sT32;
// blocks 256..880 pack weight signs into bitmasks (bits[g][d] bit j =
// W[g*32+j][d] > 0). Both memory-bound; fusing saves one dispatch gap.
// ---------------------------------------------------------------------------
__global__ __launch_bounds__(256) void mid(const double* __restrict__ part,
                                           double* __restrict__ sT64,
                                           float* __restrict__ sT32,
                                           const float* __restrict__ wts,
                                           uint32_t* __restrict__ bits) {
    int bid = blockIdx.x;
    if (bid < 256) {
        int i = bid * 256 + threadIdx.x;        // 0 .. 65535 (= w*128+b)
        double s = (part[i] + part[65536 + i]) + (part[131072 + i] + part[196608 + i]);
        sT64[i] = s;
        sT32[i] = (float)s;
    } else {
        int idx = (bid - 256) * 256 + threadIdx.x;  // 0 .. 159999 exactly
        int g = idx / Dn;
        int d = idx - g * Dn;
        uint32_t m = 0;
        #pragma unroll
        for (int j = 0; j < 32; ++j)
            m |= (wts[(size_t)(g * 32 + j) * Dn + d] > 0.0f) ? (1u << j) : 0u;
        bits[idx] = m;
    }
}

// ---------------------------------------------------------------------------
// Kernel 3: fused GEMM + sign + ambiguous-compact. Full K=512 per thread.
// Thread: one d, 16 b's as 8 f32x2 accumulators via v_pk_fma_f32.
// sT32 row pairs are wave-uniform -> forced to SGPR pairs ("s" constraint);
// per j: 1 mask test + 2 cndmask (sign pair) + 8 pk_fma = 16 MACs.
// grid (40, 8). Confident signs written directly to out; |v|<=0.25 pushed
// to the fixup list.
// ---------------------------------------------------------------------------
__global__ __launch_bounds__(256) void gemm_sign(const uint32_t* __restrict__ bits,
                                                 const float* __restrict__ sT32,
                                                 uint32_t* __restrict__ cnt,
                                                 uint32_t* __restrict__ list,
                                                 float* __restrict__ out) {
    int d = blockIdx.x * 256 + threadIdx.x;
    d = d < Dn ? d : Dn - 1;              // clamp: duplicates do identical work
    int b0 = blockIdx.y * 16;

    f32x2 acc[8];
    #pragma unroll
    for (int i = 0; i < 8; ++i) acc[i] = (f32x2){0.0f, 0.0f};
    const f32x2 pone = {1.0f, 1.0f};
    const f32x2 mone = {-1.0f, -1.0f};

    for (int g = 0; g < 16; ++g) {
        uint32_t m = bits[(size_t)g * Dn + d];
        const f32x2* base = (const f32x2*)(sT32 + (size_t)g * 32 * Bn + b0);
        #pragma unroll
        for (int j = 0; j < 32; ++j) {
            f32x2 sg = (m & (1u << j)) ? pone : mone;
            const f32x2* sp = base + j * (Bn / 2);   // row g*32+j, b0..b0+15
            #pragma unroll
            for (int i = 0; i < 8; ++i) {
                f32x2 sv = sp[i];                    // uniform -> s_load
                asm("v_pk_fma_f32 %0, %1, %2, %0"
                    : "+v"(acc[i]) : "s"(sv), "v"(sg));
            }
        }
    }

    #pragma unroll
    for (int i = 0; i < 8; ++i) {
        #pragma unroll
        for (int k = 0; k < 2; ++k) {
            float v = k ? acc[i].y : acc[i].x;
            int b = b0 + 2 * i + k;
            size_t o = (size_t)b * Dn + d;
            if (fabsf(v) > 0.25f) {
                out[o] = v > 0.0f ? 1.0f : -1.0f;
            } else {
                uint32_t u = atomicAdd(cnt, 1u);
                if (u < CAP) list[u] = (uint32_t)o;      // fixup writes out[o]
                else out[o] = v >= 0.0f ? 1.0f : -1.0f;  // unreachable safety
            }
        }
    }
}

// ---------------------------------------------------------------------------
// Kernel 4: exact fp64 recompute of ambiguous outputs. One wave per item:
// 512 terms over 64 lanes (8 each) from packed bits + L2-resident sT64,
// then fp64 butterfly reduce. ~1000 items expected.
// ---------------------------------------------------------------------------
__global__ __launch_bounds__(256) void fixup_exact(const uint32_t* __restrict__ cnt,
                                                   const uint32_t* __restrict__ list,
                                                   const uint32_t* __restrict__ bits,
                                                   const double* __restrict__ sT64,
                                                   float* __restrict__ out) {
    int lane = threadIdx.x & 63;
    int wave = blockIdx.x * 4 + (threadIdx.x >> 6);   // 0..1023
    uint32_t n = *cnt;
    if (n > CAP) n = CAP;
    for (uint32_t item = wave; item < n; item += 1024) {
        int i = (int)list[item];
        int b = i / Dn;
        int d = i - b * Dn;
        double a = 0.0;
        #pragma unroll
        for (int k = 0; k < 8; ++k) {
            int w = lane + 64 * k;
            uint32_t m = bits[(w >> 5) * Dn + d];
            double s = sT64[w * Bn + b];
            a += ((m >> (w & 31)) & 1u) ? s : -s;
        }
        #pragma unroll
        for (int off = 32; off >= 1; off >>= 1)
            a += __shfl_xor(a, off, 64);
        if (lane == 0)
            out[i] = (a > 0.0) ? 1.0f : ((a < 0.0) ? -1.0f : 0.0f);
    }
}

// ---------------------------------------------------------------------------
extern "C" void kernel_launch(void* const* d_in, const int* in_sizes, int n_in,
                              void* d_out, int out_size, void* d_ws, size_t ws_size,
                              hipStream_t stream) {
    const float* x   = (const float*)d_in[0];   // (128,128,512) f32
    const float* wts = (const float*)d_in[1];   // (512,10000)  f32, values +-1
    float* out = (float*)d_out;                 // (128,10000)  f32 signs
    char* ws = (char*)d_ws;

    // workspace layout
    double*   part = (double*)(ws);                  // 4*512*128*8 = 2,097,152 B
    double*   sT64 = (double*)(ws + 2097152);        // 524,288 B
    float*    sT32 = (float*)(ws + 2621440);         // 262,144 B
    uint32_t* bits = (uint32_t*)(ws + 2883584);      // 640,000 B
    uint32_t* cnt  = (uint32_t*)(ws + 3523584);      // 256 B (padded)
    uint32_t* list = (uint32_t*)(ws + 3523840);      // 262,144 B -> ~3.8 MB total

    reduce_h<<<512, 256, 0, stream>>>(x, part, cnt);
    mid<<<881, 256, 0, stream>>>(part, sT64, sT32, wts, bits);
    gemm_sign<<<dim3(40, 8), 256, 0, stream>>>(bits, sT32, cnt, list, out);
    fixup_exact<<<256, 256, 0, stream>>>(cnt, list, bits, sT64, out);
}

// Round 4
// 68.439 us; speedup vs baseline: 1.2251x; 1.2251x over previous
//
#include <hip/hip_runtime.h>
#include <stdint.h>

// Problem constants
constexpr int Dn = 10000;
constexpr int Bn = 128;
constexpr int Wn = 512;
constexpr int Hn = 128;
constexpr int BD = Bn * Dn;      // 1,280,000 outputs
constexpr int CAP = 65536;       // ambiguous-list capacity

typedef float f32x2 __attribute__((ext_vector_type(2)));
typedef float f32x4 __attribute__((ext_vector_type(4)));

// ---------------------------------------------------------------------------
// Kernel 1 (fused pre-pass):
//  blocks 0..511  : h-reduction. block = (b, w-quarter of 128); thread =
//                   (w-lane, h-half of 64); fp64 partial + LDS pairwise
//                   combine -> sT64[w][b], sT32[w][b]. No global partials.
//  blocks 512..1136: pack weight signs. bits[g][d] bit j = (W[g*32+j][d] > 0).
//  Also zeroes the ambiguous counter.
// ---------------------------------------------------------------------------
__global__ __launch_bounds__(256) void prep(const float* __restrict__ x,
                                            const float* __restrict__ wts,
                                            double* __restrict__ sT64,
                                            float* __restrict__ sT32,
                                            uint32_t* __restrict__ bits,
                                            uint32_t* __restrict__ cnt) {
    int bid = blockIdx.x;
    if (bid == 0 && threadIdx.x == 0) *cnt = 0;
    if (bid < 512) {
        int b  = bid >> 2;
        int w0 = (bid & 3) << 7;               // w-quarter base
        int wl = threadIdx.x & 127;
        int hh = threadIdx.x >> 7;             // 0,1 -> h 0..63 / 64..127
        const float* p = x + (size_t)b * (Hn * Wn) + (size_t)(hh * 64) * Wn + (w0 + wl);
        double a = 0.0;
        #pragma unroll 8
        for (int h = 0; h < 64; ++h) a += (double)p[(size_t)h * Wn];
        __shared__ double red[256];
        red[threadIdx.x] = a;
        __syncthreads();
        if (hh == 0) {
            double s = red[wl] + red[wl + 128];
            int w = w0 + wl;
            sT64[w * Bn + b] = s;
            sT32[w * Bn + b] = (float)s;
        }
    } else {
        int idx = (bid - 512) * 256 + (int)threadIdx.x;  // 0 .. 159999 exactly
        int g = idx / Dn;
        int d = idx - g * Dn;
        uint32_t m = 0;
        #pragma unroll
        for (int j = 0; j < 32; ++j)
            m |= (wts[(size_t)(g * 32 + j) * Dn + d] > 0.0f) ? (1u << j) : 0u;
        bits[idx] = m;
    }
}

// ---------------------------------------------------------------------------
// Kernel 2: K-split GEMM partials. Thread: one d, 16 b's (8 f32x2 accs),
// gpw*32 w's. grid (40, 8, nz) -> 1280 blocks at nz=4 = 5 waves/SIMD so the
// wave-uniform srow s_loads (SGPR) have cross-wave latency hiding.
// Per j: per-lane sign pair (cndmask) + 8 v_pk_fma_f32 = 16 MACs.
// ---------------------------------------------------------------------------
__global__ __launch_bounds__(256) void gemm_part(const uint32_t* __restrict__ bits,
                                                 const float* __restrict__ sT32,
                                                 float* __restrict__ raw, int gpw) {
    int d = blockIdx.x * 256 + (int)threadIdx.x;
    d = d < Dn ? d : Dn - 1;              // clamp: duplicates do identical work
    int b0 = blockIdx.y << 4;
    int g0 = blockIdx.z * gpw;

    f32x2 acc[8];
    #pragma unroll
    for (int i = 0; i < 8; ++i) acc[i] = (f32x2){0.0f, 0.0f};
    const f32x2 pone = {1.0f, 1.0f};
    const f32x2 mone = {-1.0f, -1.0f};

    for (int g = 0; g < gpw; ++g) {
        uint32_t m = bits[(size_t)(g0 + g) * Dn + d];
        const f32x2* base = (const f32x2*)(sT32 + (size_t)(g0 + g) * 32 * Bn + b0);
        #pragma unroll
        for (int j = 0; j < 32; ++j) {
            f32x2 sg = (m & (1u << j)) ? pone : mone;
            const f32x2* sp = base + j * (Bn / 2);   // row g*32+j, b0..b0+15
            #pragma unroll
            for (int i = 0; i < 8; ++i) {
                f32x2 sv = sp[i];                    // uniform -> s_load
                asm("v_pk_fma_f32 %0, %1, %2, %0"
                    : "+v"(acc[i]) : "s"(sv), "v"(sg));
            }
        }
    }

    float* rp = raw + (size_t)blockIdx.z * BD + (size_t)b0 * Dn + d;
    #pragma unroll
    for (int i = 0; i < 8; ++i) {
        rp[(size_t)(2 * i) * Dn]     = acc[i].x;
        rp[(size_t)(2 * i + 1) * Dn] = acc[i].y;
    }
}

// ---------------------------------------------------------------------------
// Kernel 3: combine K-split partials (float4), write sign guess for ALL
// outputs, compact ambiguous (|v| <= 0.25) indices for exact fixup.
// grid 1250*256 threads == BD/4 exactly.
// ---------------------------------------------------------------------------
__global__ __launch_bounds__(256) void combine_sign(const float* __restrict__ raw, int nz,
                                                    uint32_t* __restrict__ cnt,
                                                    uint32_t* __restrict__ list,
                                                    float* __restrict__ out) {
    size_t t = (size_t)blockIdx.x * 256 + threadIdx.x;   // 0 .. 319999
    f32x4 v = *(const f32x4*)(raw + 4 * t);
    for (int z = 1; z < nz; ++z) {
        f32x4 u = *(const f32x4*)(raw + (size_t)z * BD + 4 * t);
        v.x += u.x; v.y += u.y; v.z += u.z; v.w += u.w;
    }
    f32x4 r;
    r.x = v.x > 0.0f ? 1.0f : -1.0f;
    r.y = v.y > 0.0f ? 1.0f : -1.0f;
    r.z = v.z > 0.0f ? 1.0f : -1.0f;
    r.w = v.w > 0.0f ? 1.0f : -1.0f;
    *(f32x4*)(out + 4 * t) = r;                          // fixup overwrites listed
    #pragma unroll
    for (int k = 0; k < 4; ++k) {
        float a = v[k];
        if (fabsf(a) <= 0.25f) {
            uint32_t u = atomicAdd(cnt, 1u);
            if (u < CAP) list[u] = (uint32_t)(4 * t + k);
        }
    }
}

// ---------------------------------------------------------------------------
// Kernel 4: exact fp64 recompute of ambiguous outputs. One wave per item:
// 512 terms over 64 lanes (8 each) from packed bits + L2-resident sT64,
// then fp64 butterfly reduce. ~1000 items expected.
// ---------------------------------------------------------------------------
__global__ __launch_bounds__(256) void fixup_exact(const uint32_t* __restrict__ cnt,
                                                   const uint32_t* __restrict__ list,
                                                   const uint32_t* __restrict__ bits,
                                                   const double* __restrict__ sT64,
                                                   float* __restrict__ out) {
    int lane = threadIdx.x & 63;
    int wave = blockIdx.x * 4 + (threadIdx.x >> 6);   // 0..1023
    uint32_t n = *cnt;
    if (n > CAP) n = CAP;
    for (uint32_t item = wave; item < n; item += 1024) {
        int i = (int)list[item];
        int b = i / Dn;
        int d = i - b * Dn;
        double a = 0.0;
        #pragma unroll
        for (int k = 0; k < 8; ++k) {
            int w = lane + 64 * k;
            uint32_t m = bits[(w >> 5) * Dn + d];
            double s = sT64[w * Bn + b];
            a += ((m >> (w & 31)) & 1u) ? s : -s;
        }
        #pragma unroll
        for (int off = 32; off >= 1; off >>= 1)
            a += __shfl_xor(a, off, 64);
        if (lane == 0)
            out[i] = (a > 0.0) ? 1.0f : ((a < 0.0) ? -1.0f : 0.0f);
    }
}

// ---------------------------------------------------------------------------
extern "C" void kernel_launch(void* const* d_in, const int* in_sizes, int n_in,
                              void* d_out, int out_size, void* d_ws, size_t ws_size,
                              hipStream_t stream) {
    const float* x   = (const float*)d_in[0];   // (128,128,512) f32
    const float* wts = (const float*)d_in[1];   // (512,10000)  f32, values +-1
    float* out = (float*)d_out;                 // (128,10000)  f32 signs
    char* ws = (char*)d_ws;

    // z=4 needs ~22.2 MB of ws; fall back to z=2 (~11.93 MB, proven to fit)
    const size_t need4 = (size_t)4 * BD * 4 + 524288 + 262144 + 640000 + 256 + 262144;
    int nz  = (ws_size >= need4) ? 4 : 2;
    int gpw = 16 / nz;                          // bits-words per z-chunk

    size_t off = (size_t)nz * BD * 4;
    float*    raw  = (float*)(ws);
    double*   sT64 = (double*)(ws + off);   off += 524288;
    float*    sT32 = (float*)(ws + off);    off += 262144;
    uint32_t* bits = (uint32_t*)(ws + off); off += 640000;
    uint32_t* cnt  = (uint32_t*)(ws + off); off += 256;
    uint32_t* list = (uint32_t*)(ws + off);

    prep<<<1137, 256, 0, stream>>>(x, wts, sT64, sT32, bits, cnt);
    gemm_part<<<dim3(40, 8, nz), 256, 0, stream>>>(bits, sT32, raw, gpw);
    combine_sign<<<1250, 256, 0, stream>>>(raw, nz, cnt, list, out);
    fixup_exact<<<256, 256, 0, stream>>>(cnt, list, bits, sT64, out);
}

// Round 6
// 39.322 us; speedup vs baseline: 2.1322x; 1.7405x over previous
//
#include <hip/hip_runtime.h>
#include <stdint.h>

// Problem constants
constexpr int Dn = 10000;
constexpr int Bn = 128;
constexpr int Wn = 512;
constexpr int Hn = 128;
constexpr int CAP = 65536;       // ambiguous-list capacity

typedef float  f32x4  __attribute__((ext_vector_type(4)));
typedef short  bf16x8 __attribute__((ext_vector_type(8)));  // 8 bf16 (4 VGPRs)

__device__ inline uint16_t f32_to_bf16(float f) {           // RNE
    uint32_t u = __builtin_bit_cast(uint32_t, f);
    return (uint16_t)((u + 0x7FFFu + ((u >> 16) & 1u)) >> 16);
}
__device__ inline float bf16_to_f32(uint16_t h) {
    uint32_t u = ((uint32_t)h) << 16;
    return __builtin_bit_cast(float, u);
}

// ---------------------------------------------------------------------------
// Kernel 1 (fused pre-pass):
//  blocks 0..511  : h-reduction for (b, w-quarter). float4 loads (512B/wave
//                   contiguous), fp64 accum, LDS slice-combine. Writes:
//                   sT64[b][w] (fp64, for exact fixup) and aHi/aLo -- the
//                   bf16 hi/lo split of S in MFMA A-fragment layout:
//                   idx = ((ktile*8+mtile)*64 + lane)*8 + j, where lane =
//                   (b&15)|(((w>>3)&3)<<4), j=w&7 (lane m=l&15 holds 8
//                   consecutive k's -> one dwordx4 per fragment in gemm).
//  blocks 512..1136: pack W signs: bits[g][d] bit j = (W[g*32+j][d] > 0).
// ---------------------------------------------------------------------------
__global__ __launch_bounds__(256) void prep(const float* __restrict__ x,
                                            const float* __restrict__ wts,
                                            double* __restrict__ sT64,
                                            uint16_t* __restrict__ aHi,
                                            uint16_t* __restrict__ aLo,
                                            uint32_t* __restrict__ bits,
                                            uint32_t* __restrict__ cnt) {
    int bid = blockIdx.x;
    if (bid == 0 && threadIdx.x == 0) *cnt = 0;
    if (bid < 512) {
        int b  = bid >> 2;
        int w0 = (bid & 3) << 7;            // w-quarter base
        int wc = threadIdx.x & 31;          // float4 column: w = w0 + wc*4
        int hs = threadIdx.x >> 5;          // 8 h-slices of 16
        const f32x4* p = (const f32x4*)(x + (size_t)b * (Hn * Wn)
                                          + (size_t)(hs * 16) * Wn + w0) + wc;
        double a0 = 0, a1 = 0, a2 = 0, a3 = 0;
        #pragma unroll
        for (int h = 0; h < 16; ++h) {
            f32x4 f = p[(size_t)h * (Wn / 4)];
            a0 += (double)f.x; a1 += (double)f.y;
            a2 += (double)f.z; a3 += (double)f.w;
        }
        __shared__ double red[8][128];
        red[hs][wc * 4 + 0] = a0;
        red[hs][wc * 4 + 1] = a1;
        red[hs][wc * 4 + 2] = a2;
        red[hs][wc * 4 + 3] = a3;
        __syncthreads();
        if (threadIdx.x < 128) {
            int wl = threadIdx.x;
            double s = 0.0;
            #pragma unroll
            for (int k = 0; k < 8; ++k) s += red[k][wl];   // fixed order
            int w = w0 + wl;
            sT64[(size_t)b * Wn + w] = s;
            float s32 = (float)s;
            uint16_t hi = f32_to_bf16(s32);
            float hif = bf16_to_f32(hi);
            uint16_t lo = f32_to_bf16(s32 - hif);          // exact residual capture
            int ktile = w >> 5;
            int mtile = b >> 4;
            int lane  = (b & 15) | (((w >> 3) & 3) << 4);
            int j     = w & 7;
            size_t idx = (size_t)((ktile * 8 + mtile) * 64 + lane) * 8 + j;
            aHi[idx] = hi;
            aLo[idx] = lo;
        }
    } else {
        int idx = (bid - 512) * 256 + (int)threadIdx.x;    // 0 .. 159999 exactly
        int g = idx / Dn;
        int d = idx - g * Dn;
        uint32_t m = 0;
        #pragma unroll
        for (int j = 0; j < 32; ++j)
            m |= (wts[(size_t)(g * 32 + j) * Dn + d] > 0.0f) ? (1u << j) : 0u;
        bits[idx] = m;
    }
}

// ---------------------------------------------------------------------------
// Kernel 2: MFMA GEMM, full K=512, fused sign + ambiguous-compact.
// 1 wave/block; wave tile M=64 x N=32 (4 m-tiles x 2 n-tiles), 256 mfma.
// grid (313, 2): blockIdx.y = m-half, blockIdx.x*32 = d base (last block's
// second n-tile is fully OOB -> loads clamped, stores masked).
// B-fragments are synthesized from packed sign bits: lane l (n = l&15) needs
// k = (l>>4)*8 + j, i.e. byte (l>>4) of word bits[g][d]; +-1 bf16 pairs are
// 0xBF80BF80 with SIGN bits (15 / 31) XOR-flipped by the weight bits
// (4 VALU / u32), amortized over 8 mfma (4 m-tiles x hi/lo).
// ---------------------------------------------------------------------------
__global__ __launch_bounds__(64) void gemm_mfma(const uint32_t* __restrict__ bits,
                                                const uint16_t* __restrict__ aHi,
                                                const uint16_t* __restrict__ aLo,
                                                uint32_t* __restrict__ cnt,
                                                uint32_t* __restrict__ list,
                                                float* __restrict__ out) {
    int lane = (int)threadIdx.x;       // 0..63
    int d0 = blockIdx.x * 32;
    int wm = blockIdx.y;               // m-base = wm*64
    int ln = lane & 15;
    int lh = lane >> 4;
    int sh = lh * 8;

    int dc0 = d0 + ln;
    int dc1 = d0 + 16 + ln;
    int dc1c = dc1 < Dn ? dc1 : Dn - 1;     // clamp (last block only)

    f32x4 acc[4][2];
    #pragma unroll
    for (int mt = 0; mt < 4; ++mt)
        #pragma unroll
        for (int nt = 0; nt < 2; ++nt) acc[mt][nt] = (f32x4){0.f, 0.f, 0.f, 0.f};

    const bf16x8* Ah = (const bf16x8*)aHi;
    const bf16x8* Al = (const bf16x8*)aLo;

    #pragma unroll 4
    for (int g = 0; g < 16; ++g) {
        uint32_t wb0 = bits[(size_t)g * Dn + dc0];
        uint32_t wb1 = bits[(size_t)g * Dn + dc1c];
        bf16x8 ah[4], al[4];
        #pragma unroll
        for (int mt = 0; mt < 4; ++mt) {
            int fi = (g * 8 + wm * 4 + mt) * 64 + lane;
            ah[mt] = Ah[fi];
            al[mt] = Al[fi];
        }
        #pragma unroll
        for (int nt = 0; nt < 2; ++nt) {
            uint32_t t = ((nt ? wb1 : wb0) >> sh) & 0xFFu;
            // bit=1 -> +1.0 (0x3F80), bit=0 -> -1.0 (0xBF80): XOR sign bit.
            int bw0 = (int)(0xBF80BF80u ^ (((t & 1u) << 15) | ((t & 2u) << 30)));
            int bw1 = (int)(0xBF80BF80u ^ ((((t >> 2) & 1u) << 15) | (((t >> 3) & 1u) << 31)));
            int bw2 = (int)(0xBF80BF80u ^ ((((t >> 4) & 1u) << 15) | (((t >> 5) & 1u) << 31)));
            int bw3 = (int)(0xBF80BF80u ^ ((((t >> 6) & 1u) << 15) | (((t >> 7) & 1u) << 31)));
            union { int i[4]; bf16x8 v; } bu;
            bu.i[0] = bw0; bu.i[1] = bw1; bu.i[2] = bw2; bu.i[3] = bw3;
            bf16x8 bf = bu.v;
            #pragma unroll
            for (int mt = 0; mt < 4; ++mt) {
                acc[mt][nt] = __builtin_amdgcn_mfma_f32_16x16x32_bf16(ah[mt], bf, acc[mt][nt], 0, 0, 0);
                acc[mt][nt] = __builtin_amdgcn_mfma_f32_16x16x32_bf16(al[mt], bf, acc[mt][nt], 0, 0, 0);
            }
        }
    }

    // Epilogue: C/D layout col = lane&15, row = (lane>>4)*4 + reg [m89/m91].
    #pragma unroll
    for (int mt = 0; mt < 4; ++mt) {
        #pragma unroll
        for (int nt = 0; nt < 2; ++nt) {
            int d = d0 + nt * 16 + ln;
            if (d < Dn) {
                #pragma unroll
                for (int r = 0; r < 4; ++r) {
                    int b = wm * 64 + mt * 16 + lh * 4 + r;
                    float v = acc[mt][nt][r];
                    size_t o = (size_t)b * Dn + d;
                    out[o] = v > 0.0f ? 1.0f : -1.0f;
                    if (fabsf(v) <= 0.25f) {
                        uint32_t u = atomicAdd(cnt, 1u);
                        if (u < CAP) list[u] = (uint32_t)o;   // fixup overwrites
                    }
                }
            }
        }
    }
}

// ---------------------------------------------------------------------------
// Kernel 3: exact fp64 recompute of ambiguous outputs. One wave per item:
// 512 terms over 64 lanes (8 each) from packed bits + L2-resident sT64[b][w]
// (contiguous per item), fp64 butterfly reduce. ~1000 items expected.
// ---------------------------------------------------------------------------
__global__ __launch_bounds__(256) void fixup_exact(const uint32_t* __restrict__ cnt,
                                                   const uint32_t* __restrict__ list,
                                                   const uint32_t* __restrict__ bits,
                                                   const double* __restrict__ sT64,
                                                   float* __restrict__ out) {
    int lane = threadIdx.x & 63;
    int wave = blockIdx.x * 4 + (threadIdx.x >> 6);   // 0..1023
    uint32_t n = *cnt;
    if (n > CAP) n = CAP;
    for (uint32_t item = wave; item < n; item += 1024) {
        int i = (int)list[item];
        int b = i / Dn;
        int d = i - b * Dn;
        double a = 0.0;
        #pragma unroll
        for (int k = 0; k < 8; ++k) {
            int w = lane + 64 * k;
            uint32_t m = bits[(w >> 5) * Dn + d];
            double s = sT64[(size_t)b * Wn + w];
            a += ((m >> (w & 31)) & 1u) ? s : -s;
        }
        #pragma unroll
        for (int off = 32; off >= 1; off >>= 1)
            a += __shfl_xor(a, off, 64);
        if (lane == 0)
            out[i] = (a > 0.0) ? 1.0f : ((a < 0.0) ? -1.0f : 0.0f);
    }
}

// ---------------------------------------------------------------------------
extern "C" void kernel_launch(void* const* d_in, const int* in_sizes, int n_in,
                              void* d_out, int out_size, void* d_ws, size_t ws_size,
                              hipStream_t stream) {
    const float* x   = (const float*)d_in[0];   // (128,128,512) f32
    const float* wts = (const float*)d_in[1];   // (512,10000)  f32, values +-1
    float* out = (float*)d_out;                 // (128,10000)  f32 signs
    char* ws = (char*)d_ws;

    // workspace layout (~1.7 MB total)
    double*   sT64 = (double*)(ws);                  // 128*512*8 = 524,288 B
    uint16_t* aHi  = (uint16_t*)(ws + 524288);       // 65536*2   = 131,072 B
    uint16_t* aLo  = (uint16_t*)(ws + 655360);       // 131,072 B
    uint32_t* bits = (uint32_t*)(ws + 786432);       // 16*10000*4 = 640,000 B
    uint32_t* cnt  = (uint32_t*)(ws + 1426432);      // 256 B (padded)
    uint32_t* list = (uint32_t*)(ws + 1426688);      // 262,144 B

    prep<<<1137, 256, 0, stream>>>(x, wts, sT64, aHi, aLo, bits, cnt);
    gemm_mfma<<<dim3(313, 2), 64, 0, stream>>>(bits, aHi, aLo, cnt, list, out);
    fixup_exact<<<256, 256, 0, stream>>>(cnt, list, bits, sT64, out);
}